// Round 2
// baseline (10897.612 us; speedup 1.0000x reference)
//
#include <hip/hip_runtime.h>
#include <type_traits>

typedef __attribute__((ext_vector_type(8))) short short8;
typedef __attribute__((ext_vector_type(4))) float f32x4;

constexpr int Bsz = 128;   // batch
constexpr int Tlen = 512;  // seq len
constexpr int Hd = 1024;   // hidden
constexpr int K1 = 2048;   // L1 ring K = [h1 | y0]

__device__ __forceinline__ unsigned short f2b(float f) {
  unsigned int u = __float_as_uint(f);
  u = (u + 0x7FFFu + ((u >> 16) & 1u)) >> 16;
  return (unsigned short)u;
}
__device__ __forceinline__ unsigned int aload32(const unsigned int* p) {
  return __hip_atomic_load(p, __ATOMIC_RELAXED, __HIP_MEMORY_SCOPE_AGENT);
}
__device__ __forceinline__ void astore32(unsigned int* p, unsigned int v) {
  __hip_atomic_store(p, v, __ATOMIC_RELAXED, __HIP_MEMORY_SCOPE_AGENT);
}

// Wave w owns h-K slice [w*256,(w+1)*256) in REGISTERS (both layers) and, for
// L1, x-K slice [1024+w*256, 1024+(w+1)*256) STREAMED from L2 (read-only, so
// loads are coherence-safe regardless of fence timing).
// Coherence for ring (A) reads: plain cacheable loads + one acquire-agent
// fence (buffer_inv sc1) per grid round, after the barrier poll succeeds.
template <int LAYER>
__device__ __forceinline__ void run_layer(
    const int* __restrict__ src, const float* __restrict__ P,
    const unsigned short* __restrict__ Wh, const unsigned short* __restrict__ Wx,
    const float* __restrict__ bhh, const float* __restrict__ bih,
    float* __restrict__ dout, unsigned short* __restrict__ Ab,
    unsigned short* __restrict__ A1,
    unsigned int* __restrict__ flags,
    f32x4 (*__restrict__ red)[4][3][64],
    const int R0, const int J0, const int w, const int lane)
{
  constexpr int KSZ = LAYER ? 2048 : 1024;  // ring K
  constexpr int NKH = 8;                    // h k-steps per wave (256/32)
  constexpr int NKX = LAYER ? 8 : 0;        // x k-steps per wave
  constexpr int KE  = NKH + NKX;
  constexpr int PD  = 3;                    // A rotating-buffer depth
  constexpr int PW  = 4;                    // x-weight rotating-buffer depth
  constexpr int NQ  = LAYER ? 4 : 3;        // reduction quantities

  const int lrow = lane >> 4;
  const int lcol = lane & 15;
  const int col = J0 + lcol;

  const float bhr = bhh[col], bhz = bhh[1024 + col], bhn = bhh[2048 + col];
  float gbr = 0.f, gbz = 0.f, gbn = 0.f;
  if (LAYER) { gbr = bih[col]; gbz = bih[1024 + col]; gbn = bih[2048 + col]; }

  // ---- resident h-part weights: 24 x short8 = 96 VGPR
  short8 wBh[3][NKH];
#pragma unroll
  for (int g = 0; g < 3; ++g) {
    const unsigned short* wp = Wh + (g * 1024 + col) * 1024 + w * 256 + lrow * 8;
#pragma unroll
    for (int ks = 0; ks < NKH; ++ks)
      wBh[g][ks] = *(const short8*)(wp + ks * 32);
  }
  const unsigned short* wxp[3];
  if (LAYER) {
#pragma unroll
    for (int g = 0; g < 3; ++g)
      wxp[g] = Wx + (g * 1024 + col) * 1024 + w * 256 + lrow * 8;
  }

  const int myrow0 = R0 + w * 16 + lrow * 4;  // this wave's epilogue rows
  float hold[4] = {0.f, 0.f, 0.f, 0.f};       // h carried in fp32 registers

  for (int r = 0; r <= 512; ++r) {
    const bool active = LAYER ? (r >= 1) : (r < 512);
    if (active) {
      const bool first = LAYER ? (r == 1) : (r == 0);
      const int par = r & 1;
      const unsigned short* Acur = Ab + par * (Bsz * KSZ);
      unsigned short* Anext = Ab + (par ^ 1) * (Bsz * KSZ);

      // ---- x-weight stream prologue (read-only data, issued early)
      short8 wx[LAYER ? PW : 1][3];
      if (LAYER) {
#pragma unroll
        for (int j = 0; j < PW; ++j)
#pragma unroll
          for (int g = 0; g < 3; ++g)
            wx[j][g] = *(const short8*)(wxp[g] + j * 32);
      }

      float gpr[4], gpz[4], gpn[4];
      if (LAYER == 0) {
        int sv[4];
#pragma unroll
        for (int i = 0; i < 4; ++i) sv[i] = src[(myrow0 + i) * Tlen + r];
#pragma unroll
        for (int i = 0; i < 4; ++i) {
          const float* pr = P + sv[i] * 3072 + col;
          gpr[i] = pr[0]; gpz[i] = pr[1024]; gpn[i] = pr[2048];
        }
      } else {
#pragma unroll
        for (int i = 0; i < 4; ++i) { gpr[i] = gbr; gpz[i] = gbz; gpn[i] = gbn; }
      }

      f32x4 ar[4], az[4], anh[4], anx[4];
#pragma unroll
      for (int f = 0; f < 4; ++f) {
        ar[f]  = (f32x4){0.f, 0.f, 0.f, 0.f};
        az[f]  = (f32x4){0.f, 0.f, 0.f, 0.f};
        anh[f] = (f32x4){0.f, 0.f, 0.f, 0.f};
        anx[f] = (f32x4){0.f, 0.f, 0.f, 0.f};
      }

      const unsigned short* rowb[4];
#pragma unroll
      for (int f = 0; f < 4; ++f)
        rowb[f] = Acur + (R0 + f * 16 + lcol) * KSZ + w * 256 + lrow * 8;

      auto kloop = [&](auto kbv) {
        constexpr int kb = decltype(kbv)::value;
        short8 abuf[PD][4];   // rotating A fragments, all static-indexed
#pragma unroll
        for (int s = 0; s < PD; ++s) {
          const int ks = kb + s;
          if (ks < KE) {
#pragma unroll
            for (int f = 0; f < 4; ++f)
              abuf[s][f] = *(const short8*)(
                  rowb[f] + ks * 32 + ((LAYER && ks >= NKH) ? 768 : 0));
          }
        }
#pragma unroll
        for (int ks = kb; ks < KE; ++ks) {
          short8 br, bz, bn;
          if (ks < NKH) { br = wBh[0][ks]; bz = wBh[1][ks]; bn = wBh[2][ks]; }
          else {
            br = wx[(ks - NKH) % PW][0];
            bz = wx[(ks - NKH) % PW][1];
            bn = wx[(ks - NKH) % PW][2];
          }
#pragma unroll
          for (int f = 0; f < 4; ++f) {
            const short8 a = abuf[(ks - kb) % PD][f];
            ar[f] = __builtin_amdgcn_mfma_f32_16x16x32_bf16(a, br, ar[f], 0, 0, 0);
            az[f] = __builtin_amdgcn_mfma_f32_16x16x32_bf16(a, bz, az[f], 0, 0, 0);
            if (ks < NKH)
              anh[f] = __builtin_amdgcn_mfma_f32_16x16x32_bf16(a, bn, anh[f], 0, 0, 0);
            else
              anx[f] = __builtin_amdgcn_mfma_f32_16x16x32_bf16(a, bn, anx[f], 0, 0, 0);
          }
          const int kn = ks + PD;
          if (kn < KE) {
#pragma unroll
            for (int f = 0; f < 4; ++f)
              abuf[(ks - kb) % PD][f] = *(const short8*)(
                  rowb[f] + kn * 32 + ((LAYER && kn >= NKH) ? 768 : 0));
          }
          if (LAYER && ks >= NKH) {
            const int jn = (ks - NKH) + PW;
            if (jn < NKX) {
#pragma unroll
              for (int g = 0; g < 3; ++g)
                wx[(ks - NKH) % PW][g] = *(const short8*)(wxp[g] + jn * 32);
            }
          }
        }
      };
      if (!first) kloop(std::integral_constant<int, 0>{});
      else if (NKX > 0) kloop(std::integral_constant<int, NKH>{});
      // (L0 first step: no A reads at all; h==0 so all GEMM terms are zero)

      // ---- cross-wave reduction: wave w sends f != w, keeps f == w
#pragma unroll
      for (int f = 0; f < 4; ++f) {
        if (f != w) {
          const int sl = (f < w) ? f : f - 1;
          red[w][0][sl][lane] = ar[f];
          red[w][1][sl][lane] = az[f];
          red[w][2][sl][lane] = anh[f];
          if (NQ == 4) red[w][3][sl][lane] = anx[f];
        }
      }
      __syncthreads();
      f32x4 sr  = (f32x4){0.f, 0.f, 0.f, 0.f};
      f32x4 sz_ = (f32x4){0.f, 0.f, 0.f, 0.f};
      f32x4 snh = (f32x4){0.f, 0.f, 0.f, 0.f};
      f32x4 snx = (f32x4){0.f, 0.f, 0.f, 0.f};
#pragma unroll
      for (int f = 0; f < 4; ++f)
        if (f == w) { sr = ar[f]; sz_ = az[f]; snh = anh[f]; if (NQ == 4) snx = anx[f]; }
#pragma unroll
      for (int ww = 0; ww < 4; ++ww) {
        if (ww != w) {
          const int sl = (w < ww) ? w : w - 1;
          sr  += red[ww][0][sl][lane];
          sz_ += red[ww][1][sl][lane];
          snh += red[ww][2][sl][lane];
          if (NQ == 4) snx += red[ww][3][sl][lane];
        }
      }

      // ---- 4-wave parallel epilogue (wave w owns rows myrow0..+3, col)
      const bool lastw = LAYER ? (r == 512) : (r == 511);
#pragma unroll
      for (int i = 0; i < 4; ++i) {
        const int row = myrow0 + i;
        float rg = sr[i] + gpr[i] + bhr;
        rg = 1.f / (1.f + __expf(-rg));
        float zg = sz_[i] + gpz[i] + bhz;
        zg = 1.f / (1.f + __expf(-zg));
        const float nx = (snx[i] + gpn[i]) + rg * (snh[i] + bhn);
        const float e2 = __expf(2.f * fabsf(nx));
        const float ng = copysignf(1.f - 2.f / (e2 + 1.f), nx);
        const float hnew = (1.f - zg) * ng + zg * hold[i];
        hold[i] = hnew;
        const unsigned int hb = (unsigned int)f2b(hnew);
        const unsigned int nb = (unsigned int)__shfl_down((int)hb, 1, 64);
        if ((lcol & 1) == 0) {
          const unsigned int pv = hb | (nb << 16);
          astore32((unsigned int*)(Anext + row * KSZ + J0 + lcol), pv);
          if (LAYER == 0)
            astore32((unsigned int*)(A1 + (par ^ 1) * (Bsz * K1) +
                                     row * K1 + 1024 + J0 + lcol), pv);
        }
        if (lastw) dout[LAYER * (Bsz * Hd) + row * Hd + col] = hnew;
      }
    }

    // ---- grid barrier + per-round acquire fence (invalidates stale L1/L2 so
    // the next round's PLAIN A-loads are coherent and L2-shareable).
    if (r < 512) {
      __syncthreads();   // drains each wave's agent stores (vmcnt0 before s_barrier)
      if (w == 0) {
        const unsigned tgt = (unsigned)(r + 1);
        if (lane == 0) astore32(&flags[(unsigned)blockIdx.x * 16u], tgt);
        for (;;) {
          const unsigned m0 = aload32(&flags[(unsigned)(lane)       * 16u]);
          const unsigned m1 = aload32(&flags[(unsigned)(lane + 64)  * 16u]);
          const unsigned m2 = aload32(&flags[(unsigned)(lane + 128) * 16u]);
          const unsigned m3 = aload32(&flags[(unsigned)(lane + 192) * 16u]);
          if (__all(m0 >= tgt && m1 >= tgt && m2 >= tgt && m3 >= tgt)) break;
          __builtin_amdgcn_s_sleep(1);
        }
        __builtin_amdgcn_fence(__ATOMIC_ACQUIRE, "agent");  // buffer_inv sc1
      }
      __syncthreads();
    }
  }
}

__global__ void __launch_bounds__(256, 1) gru_persist(
    const int* __restrict__ src,
    const float* __restrict__ P,              // [512][3072] fp32 (incl. bih0)
    const unsigned short* __restrict__ Whh0b, // [3072][1024] bf16
    const unsigned short* __restrict__ Whh1b,
    const unsigned short* __restrict__ Wih1b,
    const float* __restrict__ bhh0,
    const float* __restrict__ bih1,
    const float* __restrict__ bhh1,
    float* __restrict__ dout,
    unsigned short* __restrict__ A0,
    unsigned short* __restrict__ A1,
    unsigned int* __restrict__ flags,
    int* __restrict__ taken)
{
  __shared__ f32x4 red[4][4][3][64];   // 48 KiB reduction buffer
  __shared__ int s_work;

  const int tid = threadIdx.x;

  // ---- XCD-affinity work claiming: same-XCD blocks share A-slices via L2
  // (now that A-loads are cacheable) and keep their weight slice L2-resident.
  if (tid == 0) {
    unsigned int xcc;
    asm volatile("s_getreg_b32 %0, hwreg(HW_REG_XCC_ID)" : "=s"(xcc));
    const int pref = ((int)(xcc & 7u)) * 32;
    int got = -1;
    for (int j = 0; j < 256; ++j) {
      const int idx = (pref + j) & 255;
      int expected = 0;
      if (__hip_atomic_compare_exchange_strong(&taken[idx], &expected, 1,
              __ATOMIC_RELAXED, __ATOMIC_RELAXED, __HIP_MEMORY_SCOPE_AGENT)) {
        got = idx; break;
      }
    }
    s_work = got;
  }
  __syncthreads();
  const int work = s_work;
  const int xcd_w = work >> 5;          // 0..7
  const int slot = work & 31;
  const int layer = (slot >> 4) & 1;
  const int c = xcd_w * 8 + ((slot >> 1) & 7);   // gate-triple 0..63
  const int mh = slot & 1;
  const int R0 = mh * 64;
  const int J0 = c * 16;

  const int w = tid >> 6;
  const int lane = tid & 63;

  if (layer == 0)
    run_layer<0>(src, P, Whh0b, Wih1b, bhh0, bih1, dout, A0, A1, flags, red,
                 R0, J0, w, lane);
  else
    run_layer<1>(src, P, Whh1b, Wih1b, bhh1, bih1, dout, A1, A1, flags, red,
                 R0, J0, w, lane);
}

// ---------------- prep kernels ----------------
__global__ void __launch_bounds__(256) cvt_k(const float* __restrict__ s,
                                            unsigned short* __restrict__ d, int n) {
  const int i = (blockIdx.x * 256 + threadIdx.x) * 8;
  if (i >= n) return;
  const float4 a = *(const float4*)(s + i);
  const float4 b = *(const float4*)(s + i + 4);
  short8 o;
  o[0] = (short)f2b(a.x); o[1] = (short)f2b(a.y);
  o[2] = (short)f2b(a.z); o[3] = (short)f2b(a.w);
  o[4] = (short)f2b(b.x); o[5] = (short)f2b(b.y);
  o[6] = (short)f2b(b.z); o[7] = (short)f2b(b.w);
  *(short8*)(d + i) = o;
}

__global__ void __launch_bounds__(256) pemb_k(const float* __restrict__ emb,
                                             const float* __restrict__ wih0,
                                             const float* __restrict__ bih0,
                                             float* __restrict__ P) {
  __shared__ float se[64 * 64];
  const int g = blockIdx.x * 256 + threadIdx.x;
  const int v0 = blockIdx.y * 64;
  float acc[64];
#pragma unroll
  for (int i = 0; i < 64; ++i) acc[i] = 0.f;
  for (int kb = 0; kb < 8; ++kb) {
    __syncthreads();
#pragma unroll
    for (int s = 0; s < 4; ++s) {
      const int idx = threadIdx.x + s * 256;
      const int vv = idx >> 4, k4 = (idx & 15) * 4;
      *(float4*)(se + vv * 64 + k4) =
          *(const float4*)(emb + (v0 + vv) * 512 + kb * 64 + k4);
    }
    __syncthreads();
    float4 wv[16];
#pragma unroll
    for (int j = 0; j < 16; ++j)
      wv[j] = *(const float4*)(wih0 + g * 512 + kb * 64 + j * 4);
    for (int vv = 0; vv < 64; ++vv) {
      const float* er = se + vv * 64;
      float s0 = acc[vv];
#pragma unroll
      for (int j = 0; j < 16; ++j) {
        const float4 e = *(const float4*)(er + j * 4);
        s0 += wv[j].x * e.x + wv[j].y * e.y + wv[j].z * e.z + wv[j].w * e.w;
      }
      acc[vv] = s0;
    }
  }
  const float bb = bih0[g];
  for (int vv = 0; vv < 64; ++vv) P[(v0 + vv) * 3072 + g] = acc[vv] + bb;
}

__global__ void zero_k(unsigned int* flags, int* taken) {
  const int i = threadIdx.x;           // 0..255
  for (int j = 0; j < 16; ++j) flags[i * 16 + j] = 0u;
  taken[i] = 0;
}

extern "C" void kernel_launch(void* const* d_in, const int* in_sizes, int n_in,
                              void* d_out, int out_size, void* d_ws, size_t ws_size,
                              hipStream_t stream) {
  const int* src = (const int*)d_in[0];
  const float* emb = (const float*)d_in[1];
  const float* wih0 = (const float*)d_in[2];
  const float* whh0 = (const float*)d_in[3];
  const float* bih0 = (const float*)d_in[4];
  const float* bhh0 = (const float*)d_in[5];
  const float* wih1 = (const float*)d_in[6];
  const float* whh1 = (const float*)d_in[7];
  const float* bih1 = (const float*)d_in[8];
  const float* bhh1 = (const float*)d_in[9];
  float* dout = (float*)d_out;

  char* p = (char*)d_ws;
  unsigned short* A0 = (unsigned short*)p;                       // 524288 B
  unsigned short* A1 = (unsigned short*)(p + 524288);            // 1048576 B
  unsigned short* Whh0b = (unsigned short*)(p + 1572864);        // 6291456 B
  unsigned short* Whh1b = (unsigned short*)(p + 7864320);        // 6291456 B
  unsigned short* Wih1b = (unsigned short*)(p + 14155776);       // 6291456 B
  float* P = (float*)(p + 20447232);                             // 6291456 B
  unsigned int* flags = (unsigned int*)(p + 26738688);           // 16384 B
  int* taken = (int*)(p + 26755072);                             // 1024 B

  constexpr int NW = 3072 * 1024;
  hipLaunchKernelGGL(cvt_k, dim3(NW / (256 * 8)), dim3(256), 0, stream, whh0, Whh0b, NW);
  hipLaunchKernelGGL(cvt_k, dim3(NW / (256 * 8)), dim3(256), 0, stream, whh1, Whh1b, NW);
  hipLaunchKernelGGL(cvt_k, dim3(NW / (256 * 8)), dim3(256), 0, stream, wih1, Wih1b, NW);
  hipLaunchKernelGGL(pemb_k, dim3(12, 8), dim3(256), 0, stream, emb, wih0, bih0, P);
  hipLaunchKernelGGL(zero_k, dim3(1), dim3(256), 0, stream, flags, taken);

  hipLaunchKernelGGL(gru_persist, dim3(256), dim3(256), 0, stream,
                     src, P, Whh0b, Whh1b, Wih1b, bhh0, bih1, bhh1,
                     dout, A0, A1, flags, taken);
}

// Round 3
// 8659.283 us; speedup vs baseline: 1.2585x; 1.2585x over previous
//
#include <hip/hip_runtime.h>
#include <type_traits>

typedef __attribute__((ext_vector_type(8))) short short8;
typedef __attribute__((ext_vector_type(4))) float f32x4;
typedef __attribute__((ext_vector_type(2))) unsigned long long u64x2;

constexpr int Bsz = 128;   // batch
constexpr int Tlen = 512;  // seq len
constexpr int Hd = 1024;   // hidden
constexpr int K1 = 2048;   // L1 ring K = [h1 | y0]

__device__ __forceinline__ unsigned short f2b(float f) {
  unsigned int u = __float_as_uint(f);
  u = (u + 0x7FFFu + ((u >> 16) & 1u)) >> 16;
  return (unsigned short)u;
}
__device__ __forceinline__ unsigned long long aload64(const unsigned long long* p) {
  return __hip_atomic_load(p, __ATOMIC_RELAXED, __HIP_MEMORY_SCOPE_AGENT);
}
__device__ __forceinline__ unsigned int aload32(const unsigned int* p) {
  return __hip_atomic_load(p, __ATOMIC_RELAXED, __HIP_MEMORY_SCOPE_AGENT);
}
__device__ __forceinline__ void astore32(unsigned int* p, unsigned int v) {
  __hip_atomic_store(p, v, __ATOMIC_RELAXED, __HIP_MEMORY_SCOPE_AGENT);
}

// Per-XCD broadcast staging: the 8 c-blocks of a (xcd,layer,mh) group each
// pull a disjoint 1/8 K-slice of the shared 64-row A-tile via sc1 (LLC,
// coherent), write it to a per-XCD staging tile with PLAIN stores (intra-XCD
// L2 is the coherence point — no cross-XCD traffic), sync via an 8-flag local
// barrier, then all read the full tile from L2 after an L1-only invalidate
// (fence acquire-workgroup -> buffer_inv sc0). Cuts LLC traffic 8x.
template <int LAYER>
__device__ __forceinline__ void run_layer(
    const int* __restrict__ src, const float* __restrict__ P,
    const unsigned short* __restrict__ Wh, const unsigned short* __restrict__ Wx,
    const float* __restrict__ bhh, const float* __restrict__ bih,
    float* __restrict__ dout, unsigned short* __restrict__ Ab,
    unsigned short* __restrict__ A1,
    unsigned short* __restrict__ Stile,   // this group's staging tile [64][KSZ]
    unsigned int* __restrict__ flags,
    unsigned int* __restrict__ lline,     // this group's 8 local flags (one 64B line)
    f32x4 (*__restrict__ red)[4][3][64],
    const int R0, const int J0, const int w, const int lane,
    const int m, const int tid)
{
  constexpr int KSZ = LAYER ? 2048 : 1024;  // ring K
  constexpr int NKH = 8;                    // h k-steps per wave (256/32)
  constexpr int NKX = LAYER ? 8 : 0;        // x k-steps per wave
  constexpr int KE  = NKH + NKX;
  constexpr int PD  = 3;                    // A rotating-buffer depth
  constexpr int PW  = 4;                    // x-weight rotating-buffer depth
  constexpr int NQ  = LAYER ? 4 : 3;        // reduction quantities
  // pull geometry: member m pulls K-slice [m*SLICE,(m+1)*SLICE) of 64 rows
  constexpr int SLICE = KSZ / 8;            // 128 / 256
  constexpr int CPR   = SLICE / 8;          // 16B-chunks per row: 16 / 32
  constexpr int LG    = LAYER ? 5 : 4;      // log2(CPR)
  constexpr int CH    = LAYER ? 8 : 4;      // chunks per thread

  const int lrow = lane >> 4;
  const int lcol = lane & 15;
  const int col = J0 + lcol;

  const float bhr = bhh[col], bhz = bhh[1024 + col], bhn = bhh[2048 + col];
  float gbr = 0.f, gbz = 0.f, gbn = 0.f;
  if (LAYER) { gbr = bih[col]; gbz = bih[1024 + col]; gbn = bih[2048 + col]; }

  // ---- resident h-part weights: 24 x short8 = 96 VGPR
  short8 wBh[3][NKH];
#pragma unroll
  for (int g = 0; g < 3; ++g) {
    const unsigned short* wp = Wh + (g * 1024 + col) * 1024 + w * 256 + lrow * 8;
#pragma unroll
    for (int ks = 0; ks < NKH; ++ks)
      wBh[g][ks] = *(const short8*)(wp + ks * 32);
  }
  const unsigned short* wxp[3];
  if (LAYER) {
#pragma unroll
    for (int g = 0; g < 3; ++g)
      wxp[g] = Wx + (g * 1024 + col) * 1024 + w * 256 + lrow * 8;
  }

  const int myrow0 = R0 + w * 16 + lrow * 4;  // this wave's epilogue rows
  float hold[4] = {0.f, 0.f, 0.f, 0.f};       // h carried in fp32 registers

  for (int r = 0; r <= 512; ++r) {
    const bool active = LAYER ? (r >= 1) : (r < 512);
    if (active) {
      const bool first = LAYER ? (r == 1) : (r == 0);
      const int par = r & 1;
      const unsigned short* Acur = Ab + par * (Bsz * KSZ);
      unsigned short* Anext = Ab + (par ^ 1) * (Bsz * KSZ);
      const bool doGemm = !(LAYER == 0 && first);  // L0 r0: h==0, no GEMM at all

      // ---- cooperative pull: my 1/8 K-slice, LLC -> per-XCD staging (L2)
      if (doGemm) {
#pragma unroll
        for (int s = 0; s < CH; ++s) {
          const int cid = tid + s * 256;
          const int row = cid >> LG;
          const int kk = m * SLICE + (cid & (CPR - 1)) * 8;
          if (!(LAYER && first && kk < 1024)) {   // L1 r1: h-half uninitialized
            const unsigned long long* ap = (const unsigned long long*)(
                Acur + (R0 + row) * KSZ + kk);
            u64x2 v;
            v[0] = aload64(ap);
            v[1] = aload64(ap + 1);
            *(u64x2*)(Stile + row * KSZ + kk) = v;
          }
        }
      }

      // ---- x-weight stream prologue + P-gather (overlap the pull latency)
      short8 wx[LAYER ? PW : 1][3];
      if (LAYER) {
#pragma unroll
        for (int j = 0; j < PW; ++j)
#pragma unroll
          for (int g = 0; g < 3; ++g)
            wx[j][g] = *(const short8*)(wxp[g] + j * 32);
      }

      float gpr[4], gpz[4], gpn[4];
      if (LAYER == 0) {
        int sv[4];
#pragma unroll
        for (int i = 0; i < 4; ++i) sv[i] = src[(myrow0 + i) * Tlen + r];
#pragma unroll
        for (int i = 0; i < 4; ++i) {
          const float* pr = P + sv[i] * 3072 + col;
          gpr[i] = pr[0]; gpz[i] = pr[1024]; gpn[i] = pr[2048];
        }
      } else {
#pragma unroll
        for (int i = 0; i < 4; ++i) { gpr[i] = gbr; gpz[i] = gbz; gpn[i] = gbn; }
      }

      // ---- local 8-block barrier (staging visible in this XCD's L2)
      if (doGemm) {
        __syncthreads();   // drains all 4 waves' staging stores (vmcnt0)
        if (tid == 0) astore32(&lline[m], (unsigned)(r + 1));
        if (w == 0) {
          const unsigned tgt = (unsigned)(r + 1);
          for (;;) {
            const unsigned v = (lane < 8) ? aload32(&lline[lane]) : tgt;
            if (__all(v >= tgt)) break;
          }
        }
        __syncthreads();
        // L1-only invalidate (buffer_inv sc0): next plain loads hit fresh L2.
        __builtin_amdgcn_fence(__ATOMIC_ACQUIRE, "workgroup");
      }

      f32x4 ar[4], az[4], anh[4], anx[4];
#pragma unroll
      for (int f = 0; f < 4; ++f) {
        ar[f]  = (f32x4){0.f, 0.f, 0.f, 0.f};
        az[f]  = (f32x4){0.f, 0.f, 0.f, 0.f};
        anh[f] = (f32x4){0.f, 0.f, 0.f, 0.f};
        anx[f] = (f32x4){0.f, 0.f, 0.f, 0.f};
      }

      const unsigned short* rowb[4];
#pragma unroll
      for (int f = 0; f < 4; ++f)
        rowb[f] = Stile + (f * 16 + lcol) * KSZ + w * 256 + lrow * 8;

      auto kloop = [&](auto kbv) {
        constexpr int kb = decltype(kbv)::value;
        short8 abuf[PD][4];   // rotating A fragments, all static-indexed
#pragma unroll
        for (int s = 0; s < PD; ++s) {
          const int ks = kb + s;
          if (ks < KE) {
#pragma unroll
            for (int f = 0; f < 4; ++f)
              abuf[s][f] = *(const short8*)(
                  rowb[f] + ks * 32 + ((LAYER && ks >= NKH) ? 768 : 0));
          }
        }
#pragma unroll
        for (int ks = kb; ks < KE; ++ks) {
          short8 br, bz, bn;
          if (ks < NKH) { br = wBh[0][ks]; bz = wBh[1][ks]; bn = wBh[2][ks]; }
          else {
            br = wx[(ks - NKH) % PW][0];
            bz = wx[(ks - NKH) % PW][1];
            bn = wx[(ks - NKH) % PW][2];
          }
#pragma unroll
          for (int f = 0; f < 4; ++f) {
            const short8 a = abuf[(ks - kb) % PD][f];
            ar[f] = __builtin_amdgcn_mfma_f32_16x16x32_bf16(a, br, ar[f], 0, 0, 0);
            az[f] = __builtin_amdgcn_mfma_f32_16x16x32_bf16(a, bz, az[f], 0, 0, 0);
            if (ks < NKH)
              anh[f] = __builtin_amdgcn_mfma_f32_16x16x32_bf16(a, bn, anh[f], 0, 0, 0);
            else
              anx[f] = __builtin_amdgcn_mfma_f32_16x16x32_bf16(a, bn, anx[f], 0, 0, 0);
          }
          const int kn = ks + PD;
          if (kn < KE) {
#pragma unroll
            for (int f = 0; f < 4; ++f)
              abuf[(ks - kb) % PD][f] = *(const short8*)(
                  rowb[f] + kn * 32 + ((LAYER && kn >= NKH) ? 768 : 0));
          }
          if (LAYER && ks >= NKH) {
            const int jn = (ks - NKH) + PW;
            if (jn < NKX) {
#pragma unroll
              for (int g = 0; g < 3; ++g)
                wx[(ks - NKH) % PW][g] = *(const short8*)(wxp[g] + jn * 32);
            }
          }
        }
      };
      if (doGemm) {
        if (!first) kloop(std::integral_constant<int, 0>{});
        else if (NKX > 0) kloop(std::integral_constant<int, NKH>{});
      }

      // ---- cross-wave reduction: wave w sends f != w, keeps f == w
#pragma unroll
      for (int f = 0; f < 4; ++f) {
        if (f != w) {
          const int sl = (f < w) ? f : f - 1;
          red[w][0][sl][lane] = ar[f];
          red[w][1][sl][lane] = az[f];
          red[w][2][sl][lane] = anh[f];
          if (NQ == 4) red[w][3][sl][lane] = anx[f];
        }
      }
      __syncthreads();
      f32x4 sr  = (f32x4){0.f, 0.f, 0.f, 0.f};
      f32x4 sz_ = (f32x4){0.f, 0.f, 0.f, 0.f};
      f32x4 snh = (f32x4){0.f, 0.f, 0.f, 0.f};
      f32x4 snx = (f32x4){0.f, 0.f, 0.f, 0.f};
#pragma unroll
      for (int f = 0; f < 4; ++f)
        if (f == w) { sr = ar[f]; sz_ = az[f]; snh = anh[f]; if (NQ == 4) snx = anx[f]; }
#pragma unroll
      for (int ww = 0; ww < 4; ++ww) {
        if (ww != w) {
          const int sl = (w < ww) ? w : w - 1;
          sr  += red[ww][0][sl][lane];
          sz_ += red[ww][1][sl][lane];
          snh += red[ww][2][sl][lane];
          if (NQ == 4) snx += red[ww][3][sl][lane];
        }
      }

      // ---- 4-wave parallel epilogue (wave w owns rows myrow0..+3, col)
      const bool lastw = LAYER ? (r == 512) : (r == 511);
#pragma unroll
      for (int i = 0; i < 4; ++i) {
        const int row = myrow0 + i;
        float rg = sr[i] + gpr[i] + bhr;
        rg = 1.f / (1.f + __expf(-rg));
        float zg = sz_[i] + gpz[i] + bhz;
        zg = 1.f / (1.f + __expf(-zg));
        const float nx = (snx[i] + gpn[i]) + rg * (snh[i] + bhn);
        const float e2 = __expf(2.f * fabsf(nx));
        const float ng = copysignf(1.f - 2.f / (e2 + 1.f), nx);
        const float hnew = (1.f - zg) * ng + zg * hold[i];
        hold[i] = hnew;
        const unsigned int hb = (unsigned int)f2b(hnew);
        const unsigned int nb = (unsigned int)__shfl_down((int)hb, 1, 64);
        if ((lcol & 1) == 0) {
          const unsigned int pv = hb | (nb << 16);
          astore32((unsigned int*)(Anext + row * KSZ + J0 + lcol), pv);
          if (LAYER == 0)
            astore32((unsigned int*)(A1 + (par ^ 1) * (Bsz * K1) +
                                     row * K1 + 1024 + J0 + lcol), pv);
        }
        if (lastw) dout[LAYER * (Bsz * Hd) + row * Hd + col] = hnew;
      }
    }

    // ---- grid barrier: per-block flag line + lane-parallel poll
    if (r < 512) {
      __syncthreads();   // drains each wave's ring stores (vmcnt0 before s_barrier)
      if (w == 0) {
        const unsigned tgt = (unsigned)(r + 1);
        if (lane == 0) astore32(&flags[(unsigned)blockIdx.x * 16u], tgt);
        for (;;) {
          const unsigned m0 = aload32(&flags[(unsigned)(lane)       * 16u]);
          const unsigned m1 = aload32(&flags[(unsigned)(lane + 64)  * 16u]);
          const unsigned m2 = aload32(&flags[(unsigned)(lane + 128) * 16u]);
          const unsigned m3 = aload32(&flags[(unsigned)(lane + 192) * 16u]);
          if (__all(m0 >= tgt && m1 >= tgt && m2 >= tgt && m3 >= tgt)) break;
          __builtin_amdgcn_s_sleep(1);
        }
      }
      __syncthreads();
    }
  }
}

__global__ void __launch_bounds__(256, 1) gru_persist(
    const int* __restrict__ src,
    const float* __restrict__ P,              // [512][3072] fp32 (incl. bih0)
    const unsigned short* __restrict__ Whh0b, // [3072][1024] bf16
    const unsigned short* __restrict__ Whh1b,
    const unsigned short* __restrict__ Wih1b,
    const float* __restrict__ bhh0,
    const float* __restrict__ bih1,
    const float* __restrict__ bhh1,
    float* __restrict__ dout,
    unsigned short* __restrict__ A0,
    unsigned short* __restrict__ A1,
    unsigned short* __restrict__ Stage,       // per-XCD staging, 6 MB
    unsigned int* __restrict__ flags,
    unsigned int* __restrict__ lflags,        // 32 groups x 16 dwords
    int* __restrict__ taken)
{
  __shared__ f32x4 red[4][4][3][64];   // 48 KiB reduction buffer
  __shared__ int s_work;

  const int tid = threadIdx.x;

  // ---- XCD-affinity work claiming: group members land on the same XCD so
  // staging flows through the shared intra-XCD L2.
  if (tid == 0) {
    unsigned int xcc;
    asm volatile("s_getreg_b32 %0, hwreg(HW_REG_XCC_ID)" : "=s"(xcc));
    const int pref = ((int)(xcc & 7u)) * 32;
    int got = -1;
    for (int j = 0; j < 256; ++j) {
      const int idx = (pref + j) & 255;
      int expected = 0;
      if (__hip_atomic_compare_exchange_strong(&taken[idx], &expected, 1,
              __ATOMIC_RELAXED, __ATOMIC_RELAXED, __HIP_MEMORY_SCOPE_AGENT)) {
        got = idx; break;
      }
    }
    s_work = got;
  }
  __syncthreads();
  const int work = s_work;
  const int xcd_w = work >> 5;          // 0..7
  const int slot = work & 31;
  const int layer = (slot >> 4) & 1;
  const int m = (slot >> 1) & 7;        // member index within XCD group
  const int c = xcd_w * 8 + m;          // gate-triple 0..63
  const int mh = slot & 1;
  const int R0 = mh * 64;
  const int J0 = c * 16;

  const int w = tid >> 6;
  const int lane = tid & 63;

  // staging tile for (xcd, layer, mh): L0 tiles 65536 elems, L1 tiles 131072
  unsigned short* Stile = Stage + xcd_w * 393216 +
      (layer == 0 ? mh * 65536 : 131072 + mh * 131072);
  unsigned int* lline = lflags + (xcd_w * 4 + layer * 2 + mh) * 16;

  if (layer == 0)
    run_layer<0>(src, P, Whh0b, Wih1b, bhh0, bih1, dout, A0, A1, Stile,
                 flags, lline, red, R0, J0, w, lane, m, tid);
  else
    run_layer<1>(src, P, Whh1b, Wih1b, bhh1, bih1, dout, A1, A1, Stile,
                 flags, lline, red, R0, J0, w, lane, m, tid);
}

// ---------------- prep kernels ----------------
__global__ void __launch_bounds__(256) cvt_k(const float* __restrict__ s,
                                            unsigned short* __restrict__ d, int n) {
  const int i = (blockIdx.x * 256 + threadIdx.x) * 8;
  if (i >= n) return;
  const float4 a = *(const float4*)(s + i);
  const float4 b = *(const float4*)(s + i + 4);
  short8 o;
  o[0] = (short)f2b(a.x); o[1] = (short)f2b(a.y);
  o[2] = (short)f2b(a.z); o[3] = (short)f2b(a.w);
  o[4] = (short)f2b(b.x); o[5] = (short)f2b(b.y);
  o[6] = (short)f2b(b.z); o[7] = (short)f2b(b.w);
  *(short8*)(d + i) = o;
}

__global__ void __launch_bounds__(256) pemb_k(const float* __restrict__ emb,
                                             const float* __restrict__ wih0,
                                             const float* __restrict__ bih0,
                                             float* __restrict__ P) {
  __shared__ float se[64 * 64];
  const int g = blockIdx.x * 256 + threadIdx.x;
  const int v0 = blockIdx.y * 64;
  float acc[64];
#pragma unroll
  for (int i = 0; i < 64; ++i) acc[i] = 0.f;
  for (int kb = 0; kb < 8; ++kb) {
    __syncthreads();
#pragma unroll
    for (int s = 0; s < 4; ++s) {
      const int idx = threadIdx.x + s * 256;
      const int vv = idx >> 4, k4 = (idx & 15) * 4;
      *(float4*)(se + vv * 64 + k4) =
          *(const float4*)(emb + (v0 + vv) * 512 + kb * 64 + k4);
    }
    __syncthreads();
    float4 wv[16];
#pragma unroll
    for (int j = 0; j < 16; ++j)
      wv[j] = *(const float4*)(wih0 + g * 512 + kb * 64 + j * 4);
    for (int vv = 0; vv < 64; ++vv) {
      const float* er = se + vv * 64;
      float s0 = acc[vv];
#pragma unroll
      for (int j = 0; j < 16; ++j) {
        const float4 e = *(const float4*)(er + j * 4);
        s0 += wv[j].x * e.x + wv[j].y * e.y + wv[j].z * e.z + wv[j].w * e.w;
      }
      acc[vv] = s0;
    }
  }
  const float bb = bih0[g];
  for (int vv = 0; vv < 64; ++vv) P[(v0 + vv) * 3072 + g] = acc[vv] + bb;
}

__global__ void zero_k(unsigned int* flags, int* taken, unsigned int* lflags) {
  const int i = threadIdx.x;           // 0..255
  for (int j = 0; j < 16; ++j) flags[i * 16 + j] = 0u;
  taken[i] = 0;
  lflags[i] = 0u;
  lflags[i + 256] = 0u;
}

extern "C" void kernel_launch(void* const* d_in, const int* in_sizes, int n_in,
                              void* d_out, int out_size, void* d_ws, size_t ws_size,
                              hipStream_t stream) {
  const int* src = (const int*)d_in[0];
  const float* emb = (const float*)d_in[1];
  const float* wih0 = (const float*)d_in[2];
  const float* whh0 = (const float*)d_in[3];
  const float* bih0 = (const float*)d_in[4];
  const float* bhh0 = (const float*)d_in[5];
  const float* wih1 = (const float*)d_in[6];
  const float* whh1 = (const float*)d_in[7];
  const float* bih1 = (const float*)d_in[8];
  const float* bhh1 = (const float*)d_in[9];
  float* dout = (float*)d_out;

  char* p = (char*)d_ws;
  unsigned short* A0 = (unsigned short*)p;                       // 524288 B
  unsigned short* A1 = (unsigned short*)(p + 524288);            // 1048576 B
  unsigned short* Whh0b = (unsigned short*)(p + 1572864);        // 6291456 B
  unsigned short* Whh1b = (unsigned short*)(p + 7864320);        // 6291456 B
  unsigned short* Wih1b = (unsigned short*)(p + 14155776);       // 6291456 B
  float* P = (float*)(p + 20447232);                             // 6291456 B
  unsigned int* flags = (unsigned int*)(p + 26738688);           // 16384 B
  int* taken = (int*)(p + 26755072);                             // 1024 B
  unsigned int* lflags = (unsigned int*)(p + 26756096);          // 2048 B
  unsigned short* Stage = (unsigned short*)(p + 26758144);       // 6291456 B
  // total ws use: ~31.6 MB

  constexpr int NW = 3072 * 1024;
  hipLaunchKernelGGL(cvt_k, dim3(NW / (256 * 8)), dim3(256), 0, stream, whh0, Whh0b, NW);
  hipLaunchKernelGGL(cvt_k, dim3(NW / (256 * 8)), dim3(256), 0, stream, whh1, Whh1b, NW);
  hipLaunchKernelGGL(cvt_k, dim3(NW / (256 * 8)), dim3(256), 0, stream, wih1, Wih1b, NW);
  hipLaunchKernelGGL(pemb_k, dim3(12, 8), dim3(256), 0, stream, emb, wih0, bih0, P);
  hipLaunchKernelGGL(zero_k, dim3(1), dim3(256), 0, stream, flags, taken, lflags);

  hipLaunchKernelGGL(gru_persist, dim3(256), dim3(256), 0, stream,
                     src, P, Whh0b, Whh1b, Wih1b, bhh0, bih1, bhh1,
                     dout, A0, A1, Stage, flags, lflags, taken);
}